// Round 12
// baseline (279.991 us; speedup 1.0000x reference)
//
#include <hip/hip_runtime.h>

#define N_NODES 50000
#define N_EDGES 600000
#define D 128
#define KTOT 768          // 128 self + 5*128 relation-aggregated
#define NB_SCAN 196       // ceil(50000/256)

typedef __attribute__((ext_vector_type(8))) short short8;
typedef __attribute__((ext_vector_type(4))) float float4v;

static __device__ __forceinline__ float bf2f(unsigned int u16) {
    union { unsigned int i; float f; } v; v.i = u16 << 16; return v.f;
}
static __device__ __forceinline__ unsigned short f2bf(float f) {
    union { float f; unsigned int i; } v; v.f = f;
    unsigned int u = v.i;
    return (unsigned short)((u + 0x7FFFu + ((u >> 16) & 1u)) >> 16);  // RNE
}
static __device__ __forceinline__ float h2f(unsigned int h) {
    unsigned int s = (h >> 15) & 1u, e = (h >> 10) & 0x1fu, m = h & 0x3ffu;
    unsigned int bits = (e == 0) ? (s << 31)
                                 : ((s << 31) | ((e + 112u) << 23) | (m << 13));
    union { unsigned int i; float f; } v; v.i = bits; return v.f;
}

// flags: [0]=ei int32? [1]=et int32? [2]=x fp32? [3]=B fp32? [4]=A fp32?
//        [5]=W0 fp32?  [6]=x fp16 (if not fp32)
// setup: zero flags + zero cnt (fused init_flags+zero_cnt)
__global__ __launch_bounds__(256) void setup(int* __restrict__ flags,
                                             int* __restrict__ cnt) {
    int i = blockIdx.x * 256 + threadIdx.x;
    if (i < N_NODES) cnt[i] = 0;
    if (i < 8) flags[i] = 0;
}

// ALL dtype probes in one launch; block-range partition; per-block LDS vote.
__global__ __launch_bounds__(256) void detect_all(const int* __restrict__ ei,
                                                  const int* __restrict__ et,
                                                  const unsigned int* __restrict__ x,
                                                  const unsigned int* __restrict__ B,
                                                  const unsigned int* __restrict__ A,
                                                  const unsigned int* __restrict__ W0,
                                                  int* __restrict__ flags) {
    __shared__ int sflag;
    if (threadIdx.x == 0) sflag = 0;
    __syncthreads();
    int b = blockIdx.x, acc = 0, fidx;
    if (b < 64) {                 // ei: int64 high words all zero <=> flag stays 0
        fidx = 0;
        for (int i = b * 256 + threadIdx.x; i < N_EDGES; i += 64 * 256)
            acc |= ei[2 * i + 1];
    } else if (b < 80) {          // et
        fidx = 1;
        for (int i = (b - 64) * 256 + threadIdx.x; i < N_EDGES / 2; i += 16 * 256)
            acc |= et[2 * i + 1];
    } else if (b < 96) {          // x fp32? (bf16-exponent band escape on low half)
        fidx = 2;
        for (int i = (b - 80) * 256 + threadIdx.x; i < 600000; i += 16 * 256) {
            unsigned int e = (x[i] >> 7) & 0xffu;
            acc |= (e > 0xA0u || e < 0x50u) ? 1 : 0;
        }
    } else if (b < 100) {         // B fp32?
        fidx = 3;
        for (int i = (b - 96) * 256 + threadIdx.x; i < 32768; i += 4 * 256) {
            unsigned int e = (B[i] >> 7) & 0xffu;
            acc |= (e > 0xA0u || e < 0x50u) ? 1 : 0;
        }
    } else if (b == 100) {        // A fp32?
        fidx = 4;
        for (int i = threadIdx.x; i < 10; i += 256) {
            unsigned int e = (A[i] >> 7) & 0xffu;
            acc |= (e > 0xA0u || e < 0x50u) ? 1 : 0;
        }
    } else if (b < 103) {         // W0 fp32?
        fidx = 5;
        for (int i = (b - 101) * 256 + threadIdx.x; i < 8192; i += 2 * 256) {
            unsigned int e = (W0[i] >> 7) & 0xffu;
            acc |= (e > 0xA0u || e < 0x50u) ? 1 : 0;
        }
    } else {                      // x fp16? (b in 103..118)
        fidx = 6;
        for (int i = (b - 103) * 256 + threadIdx.x; i < 300000; i += 16 * 256) {
            unsigned int el = (x[i] >> 7) & 0xffu, eh = (x[i] >> 23) & 0xffu;
            acc |= (el < 0x58u || eh < 0x58u) ? 1 : 0;
        }
    }
    if (acc) sflag = 1;           // benign race
    __syncthreads();
    if (threadIdx.x == 0 && sflag) atomicOr(flags + fidx, 1);
}

// Fused ei+et normalization + target histogram (R11: norm_all + hist).
__global__ __launch_bounds__(256) void norm_hist(const int* __restrict__ ei,
                                                 const int* __restrict__ et,
                                                 int* __restrict__ idx32,
                                                 int* __restrict__ et32,
                                                 int* __restrict__ cnt,
                                                 const int* __restrict__ flags) {
    int b = blockIdx.x;
    if (b < 4688) {
        int i = b * 256 + threadIdx.x;
        if (i < 2 * N_EDGES) {
            int v = flags[0] ? ei[i] : ei[2 * i];
            idx32[i] = v;
            if (i >= N_EDGES && (unsigned)v < (unsigned)N_NODES)
                atomicAdd(&cnt[v], 1);   // count by target
        }
    } else {
        int i = (b - 4688) * 256 + threadIdx.x;
        if (i < N_EDGES) et32[i] = flags[1] ? et[i] : et[2 * i];
    }
}

static __device__ __forceinline__ float loadw(const void* p, int idx, int f32) {
    return f32 ? ((const float*)p)[idx] : bf2f(((const unsigned short*)p)[idx]);
}

// wcatB[o][k] bf16 [128][768]: k<128 -> W0[o][k]; k=128+r*128+d -> sum_j A[r,j]B[j,o,d]
__global__ __launch_bounds__(256) void prep_wB(const void* __restrict__ A,
                                               const void* __restrict__ B,
                                               const void* __restrict__ W0,
                                               unsigned short* __restrict__ wcatB,
                                               const int* __restrict__ flags) {
    int idx = blockIdx.x * 256 + threadIdx.x;  // 98304 exact (384 blocks)
    int fB = flags[3], fA = flags[4], fW = flags[5];
    int o = idx / KTOT, k = idx % KTOT;
    float v;
    if (k < D) {
        v = loadw(W0, o * D + k, fW);
    } else {
        int r = (k - D) >> 7, d = (k - D) & 127;
        v = 0.f;
#pragma unroll
        for (int j = 0; j < 4; ++j)
            v += loadw(A, r * 4 + j, fA) * loadw(B, (j * D + o) * D + d, fB);
    }
    wcatB[idx] = f2bf(v);
}

// Tier-3 weights: wcatT6F[slot][d][o] fp32 = W_slot[o][d]
__global__ __launch_bounds__(256) void prep_wt6_direct(const void* __restrict__ A,
                                                       const void* __restrict__ B,
                                                       const void* __restrict__ W0,
                                                       float* __restrict__ wcatT6F,
                                                       const int* __restrict__ flags) {
    int idx = blockIdx.x * 256 + threadIdx.x;  // 98304 exact
    int fB = flags[3], fA = flags[4], fW = flags[5];
    int slot = idx >> 14, d = (idx >> 7) & 127, o = idx & 127;
    float v;
    if (slot == 0) {
        v = loadw(W0, o * D + d, fW);
    } else {
        int r = slot - 1;
        v = 0.f;
#pragma unroll
        for (int j = 0; j < 4; ++j)
            v += loadw(A, r * 4 + j, fA) * loadw(B, (j * D + o) * D + d, fB);
    }
    wcatT6F[idx] = v;
}

__global__ __launch_bounds__(256) void scan1(const int* __restrict__ cnt,
                                             int* __restrict__ bsum) {
    __shared__ int sh[256];
    int t = threadIdx.x, idx = blockIdx.x * 256 + t;
    sh[t] = (idx < N_NODES) ? cnt[idx] : 0;
    __syncthreads();
    for (int off = 128; off > 0; off >>= 1) {
        if (t < off) sh[t] += sh[t + off];
        __syncthreads();
    }
    if (t == 0) bsum[blockIdx.x] = sh[0];
}

__global__ __launch_bounds__(64) void scan2(const int* __restrict__ bsum,
                                            int* __restrict__ bscan,
                                            int* __restrict__ offsets) {
    if (threadIdx.x != 0) return;
    int run = 0;
    for (int b = 0; b < NB_SCAN; ++b) { bscan[b] = run; run += bsum[b]; }
    offsets[N_NODES] = run;
}

__global__ __launch_bounds__(256) void scan3(const int* __restrict__ cnt,
                                             const int* __restrict__ bscan,
                                             int* __restrict__ offsets,
                                             int* __restrict__ cursor) {
    __shared__ int sh[256];
    int t = threadIdx.x, idx = blockIdx.x * 256 + t;
    int v = (idx < N_NODES) ? cnt[idx] : 0;
    sh[t] = v;
    __syncthreads();
    for (int off = 1; off < 256; off <<= 1) {
        int a = (t >= off) ? sh[t - off] : 0;
        __syncthreads();
        sh[t] += a;
        __syncthreads();
    }
    if (idx < N_NODES) {
        int excl = sh[t] - v + bscan[blockIdx.x];
        offsets[idx] = excl;
        cursor[idx] = excl;
    }
}

__global__ __launch_bounds__(256) void place(const int* __restrict__ src,
                                             const int* __restrict__ tgt,
                                             const int* __restrict__ et,
                                             int* __restrict__ cursor,
                                             int* __restrict__ entries) {
    int e = blockIdx.x * 256 + threadIdx.x;
    if (e >= N_EDGES) return;
    int s = src[e], g = tgt[e], r = et[e];
    if ((unsigned)s >= (unsigned)N_NODES || (unsigned)g >= (unsigned)N_NODES || (unsigned)r >= 5u) return;
    int pos = atomicAdd(&cursor[g], 1);
    entries[pos] = s * 8 + r;
}

// x -> bf16 into Xcat cols 0..127 (row stride 768)
__global__ __launch_bounds__(256) void conv_x(const void* __restrict__ xraw,
                                              unsigned short* __restrict__ Xcat,
                                              const int* __restrict__ flags) {
    int idx = blockIdx.x * 256 + threadIdx.x;  // 1,600,000 exact (6250 blocks)
    int n = idx >> 5, cg = idx & 31;
    int f32 = flags[2], f16 = flags[6];
    unsigned short o0, o1, o2, o3;
    if (f32) {
        float4 v = *((const float4*)xraw + idx);
        o0 = f2bf(v.x); o1 = f2bf(v.y); o2 = f2bf(v.z); o3 = f2bf(v.w);
    } else {
        uint2 v = *((const uint2*)xraw + idx);
        if (f16) {
            o0 = f2bf(h2f(v.x & 0xffffu)); o1 = f2bf(h2f(v.x >> 16));
            o2 = f2bf(h2f(v.y & 0xffffu)); o3 = f2bf(h2f(v.y >> 16));
        } else {
            o0 = v.x & 0xffffu; o1 = v.x >> 16; o2 = v.y & 0xffffu; o3 = v.y >> 16;
        }
    }
    unsigned long long pack = (unsigned long long)o0 | ((unsigned long long)o1 << 16) |
                              ((unsigned long long)o2 << 32) | ((unsigned long long)o3 << 48);
    *(unsigned long long*)(Xcat + (size_t)n * KTOT + cg * 4) = pack;
}

// aggregate v3: 2 waves/node on CONTIGUOUS halves + ILP-4 batched gathers.
// (R11 v2's parity-stride ILP loop needed >=8 entries/wave and never fired
// at mean degree 12; contiguous batches of 4 fire from degree 4.)
#define AGG_ACC(xw)                                            \
    {                                                          \
        int r = ent & 7;                                       \
        float lo = bf2f((xw) & 0xffffu), hi = bf2f((xw) >> 16);\
        if (r == 0)      { a0 += lo; a1 += hi; }               \
        else if (r == 1) { b0 += lo; b1 += hi; }               \
        else if (r == 2) { c0 += lo; c1 += hi; }               \
        else if (r == 3) { d0 += lo; d1 += hi; }               \
        else             { e0 += lo; e1 += hi; }               \
    }

__global__ __launch_bounds__(256) void aggregate(const int* __restrict__ offsets,
                                                 const int* __restrict__ entries,
                                                 unsigned int* __restrict__ Xcat32) {
    __shared__ float part[4][5][130];   // [wave][rel][col], pad 130
    int tid = threadIdx.x;
    int wid = tid >> 6, lane = tid & 63;
    int slot = wid >> 1;                // node slot within block (0/1)
    int half = wid & 1;                 // which contiguous half
    int n = blockIdx.x * 2 + slot;      // 25000 blocks -> n < 50000 exact
    int beg = offsets[n], end = offsets[n + 1];
    int mid = (beg + end + 1) >> 1;
    int lo = half ? mid : beg, hi = half ? end : mid;
    float a0 = 0, a1 = 0, b0 = 0, b1 = 0, c0 = 0, c1 = 0, d0 = 0, d1 = 0, e0 = 0, e1 = 0;

    int i = lo;
    for (; i + 3 < hi; i += 4) {        // 4 independent gathers in flight
        int en0 = entries[i], en1 = entries[i + 1], en2 = entries[i + 2], en3 = entries[i + 3];
        unsigned int s0 = (unsigned)(en0 >> 3) < (unsigned)N_NODES ? (unsigned)(en0 >> 3) : 0u;
        unsigned int s1 = (unsigned)(en1 >> 3) < (unsigned)N_NODES ? (unsigned)(en1 >> 3) : 0u;
        unsigned int s2 = (unsigned)(en2 >> 3) < (unsigned)N_NODES ? (unsigned)(en2 >> 3) : 0u;
        unsigned int s3 = (unsigned)(en3 >> 3) < (unsigned)N_NODES ? (unsigned)(en3 >> 3) : 0u;
        unsigned int x0 = Xcat32[(size_t)s0 * 384 + lane];
        unsigned int x1 = Xcat32[(size_t)s1 * 384 + lane];
        unsigned int x2 = Xcat32[(size_t)s2 * 384 + lane];
        unsigned int x3 = Xcat32[(size_t)s3 * 384 + lane];
        { int ent = en0; AGG_ACC(x0); }
        { int ent = en1; AGG_ACC(x1); }
        { int ent = en2; AGG_ACC(x2); }
        { int ent = en3; AGG_ACC(x3); }
    }
    for (; i < hi; ++i) {
        int ent = entries[i];
        unsigned int s = (unsigned)(ent >> 3) < (unsigned)N_NODES ? (unsigned)(ent >> 3) : 0u;
        unsigned int xw = Xcat32[(size_t)s * 384 + lane];
        AGG_ACC(xw);
    }

    part[wid][0][2 * lane] = a0; part[wid][0][2 * lane + 1] = a1;
    part[wid][1][2 * lane] = b0; part[wid][1][2 * lane + 1] = b1;
    part[wid][2][2 * lane] = c0; part[wid][2][2 * lane + 1] = c1;
    part[wid][3][2 * lane] = d0; part[wid][3][2 * lane + 1] = d1;
    part[wid][4][2 * lane] = e0; part[wid][4][2 * lane + 1] = e1;
    __syncthreads();

    // combine halves + pack bf16: 640 output uints, 256 threads
    for (int u = tid; u < 640; u += 256) {
        int s = u / 320, rem = u % 320;
        int r = rem >> 6, c = rem & 63;
        float lo2 = part[2 * s][r][2 * c]     + part[2 * s + 1][r][2 * c];
        float hi2 = part[2 * s][r][2 * c + 1] + part[2 * s + 1][r][2 * c + 1];
        Xcat32[(size_t)(blockIdx.x * 2 + s) * 384 + 64 + r * 64 + c] =
            (unsigned int)f2bf(lo2) | ((unsigned int)f2bf(hi2) << 16);
    }
}

// out[50000][128] = Xcat[50000][768] @ wcatB[128][768]^T  (MFMA)
__global__ __launch_bounds__(256) void gemm_mfma(const unsigned short* __restrict__ Xcat,
                                                 const unsigned short* __restrict__ wcatB,
                                                 float* __restrict__ outF) {
    __shared__ unsigned short xs[128 * 72];
    __shared__ unsigned short wsd[128 * 72];
    int tid = threadIdx.x;
    int m0 = blockIdx.x * 128;
    int wid = tid >> 6, lane = tid & 63;
    int wm = (wid & 1) * 64, wn = (wid >> 1) * 64;
    int lm = lane & 15, kg = lane >> 4;

    float4v accf[4][4];
#pragma unroll
    for (int i = 0; i < 4; ++i)
#pragma unroll
        for (int j = 0; j < 4; ++j) accf[i][j] = (float4v){0.f, 0.f, 0.f, 0.f};

    for (int kc = 0; kc < 12; ++kc) {
        if (kc) __syncthreads();
#pragma unroll
        for (int i = 0; i < 4; ++i) {
            int c = tid + i * 256;  // 0..1023
            int row = c >> 3;
            int col = (c & 7) * 8;
            int gm = m0 + row;
            short8 xv = {0, 0, 0, 0, 0, 0, 0, 0};
            if (gm < N_NODES)
                xv = *(const short8*)(Xcat + (size_t)gm * KTOT + kc * 64 + col);
            *(short8*)(&xs[row * 72 + col]) = xv;
            short8 wv = *(const short8*)(wcatB + (size_t)row * KTOT + kc * 64 + col);
            *(short8*)(&wsd[row * 72 + col]) = wv;
        }
        __syncthreads();
#pragma unroll
        for (int kb = 0; kb < 2; ++kb) {
            int k = kb * 32 + kg * 8;
            short8 a[4], b[4];
#pragma unroll
            for (int i = 0; i < 4; ++i)
                a[i] = *(const short8*)(&xs[(wm + i * 16 + lm) * 72 + k]);
#pragma unroll
            for (int i = 0; i < 4; ++i)
                b[i] = *(const short8*)(&wsd[(wn + i * 16 + lm) * 72 + k]);
#pragma unroll
            for (int i = 0; i < 4; ++i)
#pragma unroll
                for (int j = 0; j < 4; ++j)
                    accf[i][j] = __builtin_amdgcn_mfma_f32_16x16x32_bf16(a[i], b[j], accf[i][j], 0, 0, 0);
        }
    }

    // C/D: col = lane&15, row = (lane>>4)*4 + reg
#pragma unroll
    for (int i = 0; i < 4; ++i) {
        int gmb = m0 + wm + i * 16 + kg * 4;
#pragma unroll
        for (int j = 0; j < 4; ++j) {
            int gn = wn + j * 16 + lm;
#pragma unroll
            for (int r = 0; r < 4; ++r) {
                int gm = gmb + r;
                if (gm < N_NODES) outF[(size_t)gm * D + gn] = accf[i][j][r];
            }
        }
    }
}

// ---- Tier-3 fallback (tiny ws) ----
static __device__ __forceinline__ float2 readx2(const void* x, int node, int lane,
                                                int f32, int f16) {
    if (f32) return *((const float2*)x + (size_t)node * 64 + lane);
    unsigned int w = *((const unsigned int*)x + (size_t)node * 64 + lane);
    float2 r;
    if (f16) { r.x = h2f(w & 0xffffu); r.y = h2f(w >> 16); }
    else     { r.x = bf2f(w & 0xffffu); r.y = bf2f(w >> 16); }
    return r;
}

__global__ __launch_bounds__(256) void self_raw(const void* __restrict__ x,
                                                const float* __restrict__ wcatT6F,
                                                float* __restrict__ outF,
                                                const int* __restrict__ flags) {
    int t = blockIdx.x * 256 + threadIdx.x;
    int n = t >> 6, lane = t & 63;  // 12500 blocks
    int f32 = flags[2], f16 = flags[6];
    float2 xp = readx2(x, n, lane, f32, f16);
    float m0 = 0.f, m1 = 0.f;
#pragma unroll 8
    for (int dp = 0; dp < 64; ++dp) {
        float xa = __shfl(xp.x, dp);
        float xc = __shfl(xp.y, dp);
        float2 w0 = *(const float2*)(wcatT6F + (size_t)(2 * dp) * D + 2 * lane);
        float2 w1 = *(const float2*)(wcatT6F + (size_t)(2 * dp + 1) * D + 2 * lane);
        m0 += xa * w0.x + xc * w1.x;
        m1 += xa * w0.y + xc * w1.y;
    }
    *((float2*)outF + (size_t)n * 64 + lane) = make_float2(m0, m1);
}

__global__ __launch_bounds__(256) void edge_raw(const int* __restrict__ src,
                                                const int* __restrict__ tgt,
                                                const int* __restrict__ et,
                                                const void* __restrict__ x,
                                                const float* __restrict__ wcatT6F,
                                                float* __restrict__ outF,
                                                const int* __restrict__ flags) {
    int t = blockIdx.x * 256 + threadIdx.x;
    int e = t >> 6, lane = t & 63;
    if (e >= N_EDGES) return;
    int f32 = flags[2], f16 = flags[6];
    int s = src[e], g = tgt[e], r = et[e];
    if ((unsigned)s >= (unsigned)N_NODES || (unsigned)g >= (unsigned)N_NODES || (unsigned)r >= 5u) return;
    float2 xp = readx2(x, s, lane, f32, f16);
    const float* wt = wcatT6F + (size_t)(1 + r) * D * D;
    float m0 = 0.f, m1 = 0.f;
#pragma unroll 8
    for (int dp = 0; dp < 64; ++dp) {
        float xa = __shfl(xp.x, dp);
        float xc = __shfl(xp.y, dp);
        float2 w0 = *(const float2*)(wt + (size_t)(2 * dp) * D + 2 * lane);
        float2 w1 = *(const float2*)(wt + (size_t)(2 * dp + 1) * D + 2 * lane);
        m0 += xa * w0.x + xc * w1.x;
        m1 += xa * w0.y + xc * w1.y;
    }
    float* ap = outF + (size_t)g * D + lane * 2;
    atomicAdd(ap + 0, m0);
    atomicAdd(ap + 1, m1);
}

extern "C" void kernel_launch(void* const* d_in, const int* in_sizes, int n_in,
                              void* d_out, int out_size, void* d_ws, size_t ws_size,
                              hipStream_t stream) {
    // identify inputs by element count (order-proof; all counts distinct)
    const void* x  = nullptr; const int* ei = nullptr; const int* et = nullptr;
    const void* B  = nullptr; const void* A = nullptr; const void* W0 = nullptr;
    for (int i = 0; i < n_in; ++i) {
        switch (in_sizes[i]) {
            case 6400000: x  = d_in[i]; break;
            case 1200000: ei = (const int*)d_in[i]; break;
            case 600000:  et = (const int*)d_in[i]; break;
            case 65536:   B  = d_in[i]; break;
            case 20:      A  = d_in[i]; break;
            case 16384:   W0 = d_in[i]; break;
            default: break;
        }
    }
    if (!x || !ei || !et || !B || !A || !W0) {
        x  = d_in[0]; ei = (const int*)d_in[1]; et = (const int*)d_in[2];
        B  = d_in[3]; A  = d_in[4]; W0 = d_in[5];
    }
    float* outF = (float*)d_out;  // [50000,128] fp32

    char* ws = (char*)d_ws;
    int*   flags   = (int*)(ws + 0);                           // 256 B
    float* wcatT6F = (float*)(ws + 256);                       // 393,216
    unsigned short* wcatB = (unsigned short*)(ws + 393472);    // 196,608
    int* offsets  = (int*)(ws + 590080);                       // 200,004
    int* cursor   = (int*)(ws + 790144);                       // 200,000
    int* cnt      = (int*)(ws + 990144);                       // 200,000
    int* bsum     = (int*)(ws + 1190144);                      // 784
    int* bscan    = (int*)(ws + 1191168);                      // 784
    int* entries  = (int*)(ws + 1192192);                      // 2,400,000
    int* idx32    = (int*)(ws + 3592192);                      // 4,800,000 (aliased by Xcat)
    int* et32     = (int*)(ws + 8392192);                      // 2,400,000 (aliased by Xcat)
    unsigned short* Xcat = (unsigned short*)(ws + 3592192);    // 76,800,000
    const size_t needMain = 3592192ull + 76800000ull;          // 80,392,192
    const size_t needT3   = 393472ull;

    int* src32 = idx32;
    int* tgt32 = idx32 + N_EDGES;

    setup<<<NB_SCAN, 256, 0, stream>>>(flags, cnt);
    detect_all<<<119, 256, 0, stream>>>(ei, et, (const unsigned int*)x,
                                        (const unsigned int*)B, (const unsigned int*)A,
                                        (const unsigned int*)W0, flags);

    if (ws_size >= needMain) {
        prep_wB<<<384, 256, 0, stream>>>(A, B, W0, wcatB, flags);
        norm_hist<<<7032, 256, 0, stream>>>(ei, et, idx32, et32, cnt, flags);
        scan1<<<NB_SCAN, 256, 0, stream>>>(cnt, bsum);
        scan2<<<1, 64, 0, stream>>>(bsum, bscan, offsets);
        scan3<<<NB_SCAN, 256, 0, stream>>>(cnt, bscan, offsets, cursor);
        place<<<2344, 256, 0, stream>>>(src32, tgt32, et32, cursor, entries);
        conv_x<<<6250, 256, 0, stream>>>(x, Xcat, flags);
        aggregate<<<25000, 256, 0, stream>>>(offsets, entries, (unsigned int*)Xcat);
        gemm_mfma<<<391, 256, 0, stream>>>(Xcat, wcatB, outF);
    } else if (ws_size >= needT3) {
        prep_wt6_direct<<<384, 256, 0, stream>>>(A, B, W0, wcatT6F, flags);
        self_raw<<<12500, 256, 0, stream>>>(x, wcatT6F, outF, flags);
        edge_raw<<<150000, 256, 0, stream>>>(ei, ei + N_EDGES, et, x, wcatT6F, outF, flags);
    }
}

// Round 14
// 260.587 us; speedup vs baseline: 1.0745x; 1.0745x over previous
//
#include <hip/hip_runtime.h>

#define N_NODES 50000
#define N_EDGES 600000
#define D 128
#define KTOT 768          // 128 self + 5*128 relation-aggregated
#define NB_SCAN 196       // ceil(50000/256)

typedef __attribute__((ext_vector_type(8))) short short8;
typedef __attribute__((ext_vector_type(4))) float float4v;

static __device__ __forceinline__ float bf2f(unsigned int u16) {
    union { unsigned int i; float f; } v; v.i = u16 << 16; return v.f;
}
static __device__ __forceinline__ unsigned short f2bf(float f) {
    union { float f; unsigned int i; } v; v.f = f;
    unsigned int u = v.i;
    return (unsigned short)((u + 0x7FFFu + ((u >> 16) & 1u)) >> 16);  // RNE
}
static __device__ __forceinline__ float h2f(unsigned int h) {
    unsigned int s = (h >> 15) & 1u, e = (h >> 10) & 0x1fu, m = h & 0x3ffu;
    unsigned int bits = (e == 0) ? (s << 31)
                                 : ((s << 31) | ((e + 112u) << 23) | (m << 13));
    union { unsigned int i; float f; } v; v.i = bits; return v.f;
}

// flags: [0]=ei int32? [1]=et int32? [2]=x fp32? [3]=B fp32? [4]=A fp32?
//        [5]=W0 fp32?  [6]=x fp16 (if not fp32)
__global__ __launch_bounds__(256) void setup(int* __restrict__ flags,
                                             int* __restrict__ cnt) {
    int i = blockIdx.x * 256 + threadIdx.x;
    if (i < N_NODES) cnt[i] = 0;
    if (i < 8) flags[i] = 0;
}

// ALL dtype probes in one launch; block-range partition; per-block LDS vote.
__global__ __launch_bounds__(256) void detect_all(const int* __restrict__ ei,
                                                  const int* __restrict__ et,
                                                  const unsigned int* __restrict__ x,
                                                  const unsigned int* __restrict__ B,
                                                  const unsigned int* __restrict__ A,
                                                  const unsigned int* __restrict__ W0,
                                                  int* __restrict__ flags) {
    __shared__ int sflag;
    if (threadIdx.x == 0) sflag = 0;
    __syncthreads();
    int b = blockIdx.x, acc = 0, fidx;
    if (b < 64) {                 // ei: int64 high words all zero <=> flag stays 0
        fidx = 0;
        for (int i = b * 256 + threadIdx.x; i < N_EDGES; i += 64 * 256)
            acc |= ei[2 * i + 1];
    } else if (b < 80) {          // et
        fidx = 1;
        for (int i = (b - 64) * 256 + threadIdx.x; i < N_EDGES / 2; i += 16 * 256)
            acc |= et[2 * i + 1];
    } else if (b < 96) {          // x fp32? (bf16-exponent band escape on low half)
        fidx = 2;
        for (int i = (b - 80) * 256 + threadIdx.x; i < 600000; i += 16 * 256) {
            unsigned int e = (x[i] >> 7) & 0xffu;
            acc |= (e > 0xA0u || e < 0x50u) ? 1 : 0;
        }
    } else if (b < 100) {         // B fp32?
        fidx = 3;
        for (int i = (b - 96) * 256 + threadIdx.x; i < 32768; i += 4 * 256) {
            unsigned int e = (B[i] >> 7) & 0xffu;
            acc |= (e > 0xA0u || e < 0x50u) ? 1 : 0;
        }
    } else if (b == 100) {        // A fp32?
        fidx = 4;
        for (int i = threadIdx.x; i < 10; i += 256) {
            unsigned int e = (A[i] >> 7) & 0xffu;
            acc |= (e > 0xA0u || e < 0x50u) ? 1 : 0;
        }
    } else if (b < 103) {         // W0 fp32?
        fidx = 5;
        for (int i = (b - 101) * 256 + threadIdx.x; i < 8192; i += 2 * 256) {
            unsigned int e = (W0[i] >> 7) & 0xffu;
            acc |= (e > 0xA0u || e < 0x50u) ? 1 : 0;
        }
    } else {                      // x fp16? (b in 103..118)
        fidx = 6;
        for (int i = (b - 103) * 256 + threadIdx.x; i < 300000; i += 16 * 256) {
            unsigned int el = (x[i] >> 7) & 0xffu, eh = (x[i] >> 23) & 0xffu;
            acc |= (el < 0x58u || eh < 0x58u) ? 1 : 0;
        }
    }
    if (acc) sflag = 1;           // benign race
    __syncthreads();
    if (threadIdx.x == 0 && sflag) atomicOr(flags + fidx, 1);
}

static __device__ __forceinline__ float loadw(const void* p, int idx, int f32) {
    return f32 ? ((const float*)p)[idx] : bf2f(((const unsigned short*)p)[idx]);
}

// Fused: ei+et normalization + target histogram + weight build (flag-dep only).
// blocks 0..4687: ei; 4688..7031: et; 7032..7415: wcatB.
__global__ __launch_bounds__(256) void norm_hist_prep(const int* __restrict__ ei,
                                                      const int* __restrict__ et,
                                                      int* __restrict__ idx32,
                                                      int* __restrict__ et32,
                                                      int* __restrict__ cnt,
                                                      const void* __restrict__ A,
                                                      const void* __restrict__ B,
                                                      const void* __restrict__ W0,
                                                      unsigned short* __restrict__ wcatB,
                                                      const int* __restrict__ flags) {
    int b = blockIdx.x;
    if (b < 4688) {
        int i = b * 256 + threadIdx.x;
        if (i < 2 * N_EDGES) {
            int v = flags[0] ? ei[i] : ei[2 * i];
            idx32[i] = v;
            if (i >= N_EDGES && (unsigned)v < (unsigned)N_NODES)
                atomicAdd(&cnt[v], 1);   // count by target
        }
    } else if (b < 7032) {
        int i = (b - 4688) * 256 + threadIdx.x;
        if (i < N_EDGES) et32[i] = flags[1] ? et[i] : et[2 * i];
    } else {
        int idx = (b - 7032) * 256 + threadIdx.x;  // 98304 exact
        int fB = flags[3], fA = flags[4], fW = flags[5];
        int o = idx / KTOT, k = idx % KTOT;
        float v;
        if (k < D) {
            v = loadw(W0, o * D + k, fW);
        } else {
            int r = (k - D) >> 7, d = (k - D) & 127;
            v = 0.f;
#pragma unroll
            for (int j = 0; j < 4; ++j)
                v += loadw(A, r * 4 + j, fA) * loadw(B, (j * D + o) * D + d, fB);
        }
        wcatB[idx] = f2bf(v);
    }
}

// Tier-3 weights: wcatT6F[slot][d][o] fp32 = W_slot[o][d]
__global__ __launch_bounds__(256) void prep_wt6_direct(const void* __restrict__ A,
                                                       const void* __restrict__ B,
                                                       const void* __restrict__ W0,
                                                       float* __restrict__ wcatT6F,
                                                       const int* __restrict__ flags) {
    int idx = blockIdx.x * 256 + threadIdx.x;  // 98304 exact
    int fB = flags[3], fA = flags[4], fW = flags[5];
    int slot = idx >> 14, d = (idx >> 7) & 127, o = idx & 127;
    float v;
    if (slot == 0) {
        v = loadw(W0, o * D + d, fW);
    } else {
        int r = slot - 1;
        v = 0.f;
#pragma unroll
        for (int j = 0; j < 4; ++j)
            v += loadw(A, r * 4 + j, fA) * loadw(B, (j * D + o) * D + d, fB);
    }
    wcatT6F[idx] = v;
}

__global__ __launch_bounds__(256) void scan1(const int* __restrict__ cnt,
                                             int* __restrict__ bsum) {
    __shared__ int sh[256];
    int t = threadIdx.x, idx = blockIdx.x * 256 + t;
    sh[t] = (idx < N_NODES) ? cnt[idx] : 0;
    __syncthreads();
    for (int off = 128; off > 0; off >>= 1) {
        if (t < off) sh[t] += sh[t + off];
        __syncthreads();
    }
    if (t == 0) bsum[blockIdx.x] = sh[0];
}

__global__ __launch_bounds__(64) void scan2(const int* __restrict__ bsum,
                                            int* __restrict__ bscan,
                                            int* __restrict__ offsets) {
    if (threadIdx.x != 0) return;
    int run = 0;
    for (int b = 0; b < NB_SCAN; ++b) { bscan[b] = run; run += bsum[b]; }
    offsets[N_NODES] = run;
}

__global__ __launch_bounds__(256) void scan3(const int* __restrict__ cnt,
                                             const int* __restrict__ bscan,
                                             int* __restrict__ offsets,
                                             int* __restrict__ cursor) {
    __shared__ int sh[256];
    int t = threadIdx.x, idx = blockIdx.x * 256 + t;
    int v = (idx < N_NODES) ? cnt[idx] : 0;
    sh[t] = v;
    __syncthreads();
    for (int off = 1; off < 256; off <<= 1) {
        int a = (t >= off) ? sh[t - off] : 0;
        __syncthreads();
        sh[t] += a;
        __syncthreads();
    }
    if (idx < N_NODES) {
        int excl = sh[t] - v + bscan[blockIdx.x];
        offsets[idx] = excl;
        cursor[idx] = excl;
    }
}

// place MUST complete before conv_x: idx32/et32 alias the Xcat buffer
// (R13 fused them -> conv clobbered indices while place read them; 0.33 err).
__global__ __launch_bounds__(256) void place(const int* __restrict__ src,
                                             const int* __restrict__ tgt,
                                             const int* __restrict__ et,
                                             int* __restrict__ cursor,
                                             int* __restrict__ entries) {
    int e = blockIdx.x * 256 + threadIdx.x;
    if (e >= N_EDGES) return;
    int s = src[e], g = tgt[e], r = et[e];
    if ((unsigned)s >= (unsigned)N_NODES || (unsigned)g >= (unsigned)N_NODES || (unsigned)r >= 5u) return;
    int pos = atomicAdd(&cursor[g], 1);
    entries[pos] = s * 8 + r;
}

// x -> bf16 into Xcat cols 0..127 (row stride 768).  Runs AFTER place.
__global__ __launch_bounds__(256) void conv_x(const void* __restrict__ xraw,
                                              unsigned short* __restrict__ Xcat,
                                              const int* __restrict__ flags) {
    int idx = blockIdx.x * 256 + threadIdx.x;  // 1,600,000 exact (6250 blocks)
    int n = idx >> 5, cg = idx & 31;
    int f32 = flags[2], f16 = flags[6];
    unsigned short o0, o1, o2, o3;
    if (f32) {
        float4 v = *((const float4*)xraw + idx);
        o0 = f2bf(v.x); o1 = f2bf(v.y); o2 = f2bf(v.z); o3 = f2bf(v.w);
    } else {
        uint2 v = *((const uint2*)xraw + idx);
        if (f16) {
            o0 = f2bf(h2f(v.x & 0xffffu)); o1 = f2bf(h2f(v.x >> 16));
            o2 = f2bf(h2f(v.y & 0xffffu)); o3 = f2bf(h2f(v.y >> 16));
        } else {
            o0 = v.x & 0xffffu; o1 = v.x >> 16; o2 = v.y & 0xffffu; o3 = v.y >> 16;
        }
    }
    unsigned long long pack = (unsigned long long)o0 | ((unsigned long long)o1 << 16) |
                              ((unsigned long long)o2 << 32) | ((unsigned long long)o3 << 48);
    *(unsigned long long*)(Xcat + (size_t)n * KTOT + cg * 4) = pack;
}

// aggregate v4: 2 waves/node, entries fetched ONCE per wave via coalesced
// lane-load then __shfl broadcast -> all gathers in a batch are independent.
#define AGG_ACC(xw)                                            \
    {                                                          \
        int r = ent & 7;                                       \
        float flo = bf2f((xw) & 0xffffu), fhi = bf2f((xw) >> 16);\
        if (r == 0)      { a0 += flo; a1 += fhi; }             \
        else if (r == 1) { b0 += flo; b1 += fhi; }             \
        else if (r == 2) { c0 += flo; c1 += fhi; }             \
        else if (r == 3) { d0 += flo; d1 += fhi; }             \
        else             { e0 += flo; e1 += fhi; }             \
    }

#define AGG_GATHER(en) Xcat32[(size_t)((unsigned)((en) >> 3) < (unsigned)N_NODES ? (unsigned)((en) >> 3) : 0u) * 384 + lane]

__global__ __launch_bounds__(256) void aggregate(const int* __restrict__ offsets,
                                                 const int* __restrict__ entries,
                                                 unsigned int* __restrict__ Xcat32) {
    __shared__ float part[4][5][130];   // [wave][rel][col], pad 130
    int tid = threadIdx.x;
    int wid = tid >> 6, lane = tid & 63;
    int slot = wid >> 1;                // node slot within block (0/1)
    int half = wid & 1;                 // which contiguous half
    int n = blockIdx.x * 2 + slot;      // 25000 blocks -> n < 50000 exact
    int beg = offsets[n], end = offsets[n + 1];
    int mid = (beg + end + 1) >> 1;
    int lo = half ? mid : beg, hi = half ? end : mid;
    float a0 = 0, a1 = 0, b0 = 0, b1 = 0, c0 = 0, c1 = 0, d0 = 0, d1 = 0, e0 = 0, e1 = 0;

    for (int base = lo; base < hi; base += 64) {
        int navail = hi - base;
        int cnt = navail < 64 ? navail : 64;
        int eidx = base + (lane < cnt ? lane : cnt - 1);
        int eload = entries[eidx];       // ONE coalesced load covers the chunk
        int j = 0;
        for (; j + 3 < cnt; j += 4) {    // 4 independent gathers, no mem dep
            int en0 = __shfl(eload, j), en1 = __shfl(eload, j + 1);
            int en2 = __shfl(eload, j + 2), en3 = __shfl(eload, j + 3);
            unsigned int x0 = AGG_GATHER(en0);
            unsigned int x1 = AGG_GATHER(en1);
            unsigned int x2 = AGG_GATHER(en2);
            unsigned int x3 = AGG_GATHER(en3);
            { int ent = en0; AGG_ACC(x0); }
            { int ent = en1; AGG_ACC(x1); }
            { int ent = en2; AGG_ACC(x2); }
            { int ent = en3; AGG_ACC(x3); }
        }
        for (; j < cnt; ++j) {
            int ent = __shfl(eload, j);
            unsigned int xw = AGG_GATHER(ent);
            AGG_ACC(xw);
        }
    }

    part[wid][0][2 * lane] = a0; part[wid][0][2 * lane + 1] = a1;
    part[wid][1][2 * lane] = b0; part[wid][1][2 * lane + 1] = b1;
    part[wid][2][2 * lane] = c0; part[wid][2][2 * lane + 1] = c1;
    part[wid][3][2 * lane] = d0; part[wid][3][2 * lane + 1] = d1;
    part[wid][4][2 * lane] = e0; part[wid][4][2 * lane + 1] = e1;
    __syncthreads();

    for (int u = tid; u < 640; u += 256) {
        int s = u / 320, rem = u % 320;
        int r = rem >> 6, c = rem & 63;
        float lo2 = part[2 * s][r][2 * c]     + part[2 * s + 1][r][2 * c];
        float hi2 = part[2 * s][r][2 * c + 1] + part[2 * s + 1][r][2 * c + 1];
        Xcat32[(size_t)(blockIdx.x * 2 + s) * 384 + 64 + r * 64 + c] =
            (unsigned int)f2bf(lo2) | ((unsigned int)f2bf(hi2) << 16);
    }
}

// out = Xcat[50000][768] @ wcatB[128][768]^T.  64-row tiles (782 blocks).
__global__ __launch_bounds__(256) void gemm_mfma(const unsigned short* __restrict__ Xcat,
                                                 const unsigned short* __restrict__ wcatB,
                                                 float* __restrict__ outF) {
    __shared__ unsigned short xs[64 * 72];
    __shared__ unsigned short wsd[128 * 72];
    int tid = threadIdx.x;
    int m0 = blockIdx.x * 64;
    int wid = tid >> 6, lane = tid & 63;
    int wm = (wid & 1) * 32, wn = (wid >> 1) * 64;
    int lm = lane & 15, kg = lane >> 4;

    float4v accf[2][4];
#pragma unroll
    for (int i = 0; i < 2; ++i)
#pragma unroll
        for (int j = 0; j < 4; ++j) accf[i][j] = (float4v){0.f, 0.f, 0.f, 0.f};

    for (int kc = 0; kc < 12; ++kc) {
        if (kc) __syncthreads();
#pragma unroll
        for (int i = 0; i < 2; ++i) {   // X: 64 rows x 64 cols = 512 chunks
            int c = tid + i * 256;
            int row = c >> 3, col = (c & 7) * 8;
            int gm = m0 + row;
            short8 xv = {0, 0, 0, 0, 0, 0, 0, 0};
            if (gm < N_NODES)
                xv = *(const short8*)(Xcat + (size_t)gm * KTOT + kc * 64 + col);
            *(short8*)(&xs[row * 72 + col]) = xv;
        }
#pragma unroll
        for (int i = 0; i < 4; ++i) {   // W: 128 rows x 64 cols = 1024 chunks
            int c = tid + i * 256;
            int row = c >> 3, col = (c & 7) * 8;
            short8 wv = *(const short8*)(wcatB + (size_t)row * KTOT + kc * 64 + col);
            *(short8*)(&wsd[row * 72 + col]) = wv;
        }
        __syncthreads();
#pragma unroll
        for (int kb = 0; kb < 2; ++kb) {
            int k = kb * 32 + kg * 8;
            short8 a[2], b[4];
#pragma unroll
            for (int i = 0; i < 2; ++i)
                a[i] = *(const short8*)(&xs[(wm + i * 16 + lm) * 72 + k]);
#pragma unroll
            for (int j = 0; j < 4; ++j)
                b[j] = *(const short8*)(&wsd[(wn + j * 16 + lm) * 72 + k]);
#pragma unroll
            for (int i = 0; i < 2; ++i)
#pragma unroll
                for (int j = 0; j < 4; ++j)
                    accf[i][j] = __builtin_amdgcn_mfma_f32_16x16x32_bf16(a[i], b[j], accf[i][j], 0, 0, 0);
        }
    }

    // C/D: col = lane&15, row = (lane>>4)*4 + reg
#pragma unroll
    for (int i = 0; i < 2; ++i) {
        int gmb = m0 + wm + i * 16 + kg * 4;
#pragma unroll
        for (int j = 0; j < 4; ++j) {
            int gn = wn + j * 16 + lm;
#pragma unroll
            for (int r = 0; r < 4; ++r) {
                int gm = gmb + r;
                if (gm < N_NODES) outF[(size_t)gm * D + gn] = accf[i][j][r];
            }
        }
    }
}

// ---- Tier-3 fallback (tiny ws) ----
static __device__ __forceinline__ float2 readx2(const void* x, int node, int lane,
                                                int f32, int f16) {
    if (f32) return *((const float2*)x + (size_t)node * 64 + lane);
    unsigned int w = *((const unsigned int*)x + (size_t)node * 64 + lane);
    float2 r;
    if (f16) { r.x = h2f(w & 0xffffu); r.y = h2f(w >> 16); }
    else     { r.x = bf2f(w & 0xffffu); r.y = bf2f(w >> 16); }
    return r;
}

__global__ __launch_bounds__(256) void self_raw(const void* __restrict__ x,
                                                const float* __restrict__ wcatT6F,
                                                float* __restrict__ outF,
                                                const int* __restrict__ flags) {
    int t = blockIdx.x * 256 + threadIdx.x;
    int n = t >> 6, lane = t & 63;
    int f32 = flags[2], f16 = flags[6];
    float2 xp = readx2(x, n, lane, f32, f16);
    float m0 = 0.f, m1 = 0.f;
#pragma unroll 8
    for (int dp = 0; dp < 64; ++dp) {
        float xa = __shfl(xp.x, dp);
        float xc = __shfl(xp.y, dp);
        float2 w0 = *(const float2*)(wcatT6F + (size_t)(2 * dp) * D + 2 * lane);
        float2 w1 = *(const float2*)(wcatT6F + (size_t)(2 * dp + 1) * D + 2 * lane);
        m0 += xa * w0.x + xc * w1.x;
        m1 += xa * w0.y + xc * w1.y;
    }
    *((float2*)outF + (size_t)n * 64 + lane) = make_float2(m0, m1);
}

__global__ __launch_bounds__(256) void edge_raw(const int* __restrict__ src,
                                                const int* __restrict__ tgt,
                                                const int* __restrict__ et,
                                                const void* __restrict__ x,
                                                const float* __restrict__ wcatT6F,
                                                float* __restrict__ outF,
                                                const int* __restrict__ flags) {
    int t = blockIdx.x * 256 + threadIdx.x;
    int e = t >> 6, lane = t & 63;
    if (e >= N_EDGES) return;
    int f32 = flags[2], f16 = flags[6];
    int s = src[e], g = tgt[e], r = et[e];
    if ((unsigned)s >= (unsigned)N_NODES || (unsigned)g >= (unsigned)N_NODES || (unsigned)r >= 5u) return;
    float2 xp = readx2(x, s, lane, f32, f16);
    const float* wt = wcatT6F + (size_t)(1 + r) * D * D;
    float m0 = 0.f, m1 = 0.f;
#pragma unroll 8
    for (int dp = 0; dp < 64; ++dp) {
        float xa = __shfl(xp.x, dp);
        float xc = __shfl(xp.y, dp);
        float2 w0 = *(const float2*)(wt + (size_t)(2 * dp) * D + 2 * lane);
        float2 w1 = *(const float2*)(wt + (size_t)(2 * dp + 1) * D + 2 * lane);
        m0 += xa * w0.x + xc * w1.x;
        m1 += xa * w0.y + xc * w1.y;
    }
    float* ap = outF + (size_t)g * D + lane * 2;
    atomicAdd(ap + 0, m0);
    atomicAdd(ap + 1, m1);
}

extern "C" void kernel_launch(void* const* d_in, const int* in_sizes, int n_in,
                              void* d_out, int out_size, void* d_ws, size_t ws_size,
                              hipStream_t stream) {
    // identify inputs by element count (order-proof; all counts distinct)
    const void* x  = nullptr; const int* ei = nullptr; const int* et = nullptr;
    const void* B  = nullptr; const void* A = nullptr; const void* W0 = nullptr;
    for (int i = 0; i < n_in; ++i) {
        switch (in_sizes[i]) {
            case 6400000: x  = d_in[i]; break;
            case 1200000: ei = (const int*)d_in[i]; break;
            case 600000:  et = (const int*)d_in[i]; break;
            case 65536:   B  = d_in[i]; break;
            case 20:      A  = d_in[i]; break;
            case 16384:   W0 = d_in[i]; break;
            default: break;
        }
    }
    if (!x || !ei || !et || !B || !A || !W0) {
        x  = d_in[0]; ei = (const int*)d_in[1]; et = (const int*)d_in[2];
        B  = d_in[3]; A  = d_in[4]; W0 = d_in[5];
    }
    float* outF = (float*)d_out;  // [50000,128] fp32

    char* ws = (char*)d_ws;
    int*   flags   = (int*)(ws + 0);                           // 256 B
    float* wcatT6F = (float*)(ws + 256);                       // 393,216
    unsigned short* wcatB = (unsigned short*)(ws + 393472);    // 196,608
    int* offsets  = (int*)(ws + 590080);                       // 200,004
    int* cursor   = (int*)(ws + 790144);                       // 200,000
    int* cnt      = (int*)(ws + 990144);                       // 200,000
    int* bsum     = (int*)(ws + 1190144);                      // 784
    int* bscan    = (int*)(ws + 1191168);                      // 784
    int* entries  = (int*)(ws + 1192192);                      // 2,400,000
    int* idx32    = (int*)(ws + 3592192);                      // 4,800,000 (aliased by Xcat)
    int* et32     = (int*)(ws + 8392192);                      // 2,400,000 (aliased by Xcat)
    unsigned short* Xcat = (unsigned short*)(ws + 3592192);    // 76,800,000
    const size_t needMain = 3592192ull + 76800000ull;          // 80,392,192
    const size_t needT3   = 393472ull;

    int* src32 = idx32;
    int* tgt32 = idx32 + N_EDGES;

    setup<<<NB_SCAN, 256, 0, stream>>>(flags, cnt);
    detect_all<<<119, 256, 0, stream>>>(ei, et, (const unsigned int*)x,
                                        (const unsigned int*)B, (const unsigned int*)A,
                                        (const unsigned int*)W0, flags);

    if (ws_size >= needMain) {
        norm_hist_prep<<<7416, 256, 0, stream>>>(ei, et, idx32, et32, cnt,
                                                 A, B, W0, wcatB, flags);
        scan1<<<NB_SCAN, 256, 0, stream>>>(cnt, bsum);
        scan2<<<1, 64, 0, stream>>>(bsum, bscan, offsets);
        scan3<<<NB_SCAN, 256, 0, stream>>>(cnt, bscan, offsets, cursor);
        place<<<2344, 256, 0, stream>>>(src32, tgt32, et32, cursor, entries);
        // conv_x clobbers idx32/et32 (Xcat aliases them) — MUST follow place.
        conv_x<<<6250, 256, 0, stream>>>(x, Xcat, flags);
        aggregate<<<25000, 256, 0, stream>>>(offsets, entries, (unsigned int*)Xcat);
        gemm_mfma<<<782, 256, 0, stream>>>(Xcat, wcatB, outF);
    } else if (ws_size >= needT3) {
        prep_wt6_direct<<<384, 256, 0, stream>>>(A, B, W0, wcatT6F, flags);
        self_raw<<<12500, 256, 0, stream>>>(x, wcatT6F, outF, flags);
        edge_raw<<<150000, 256, 0, stream>>>(ei, ei + N_EDGES, et, x, wcatT6F, outF, flags);
    }
}